// Round 1
// 434.806 us; speedup vs baseline: 1.0081x; 1.0081x over previous
//
#include <hip/hip_runtime.h>

// CRY gate, DIM=2, N=24, C=0, T=1, J=1, K=2, B=2.
// d = g*2^23 + t*2^22 + s (big-endian digits), flat = d*2 + batch.
// Merged index i = 2s+batch in [0, 2^23): contiguous within each (g,t) quadrant.
// Quadrant strides (floats): t -> 2^23, g -> 2^24. Output real at 0, imag at 2^25.
// g=0: identity copy. g=1: [out_t0; out_t1] = [[c,-s],[-s,c]] [in_t0; in_t1].
//
// This version: clang ext_vector float4 + nontemporal loads/stores (zero-reuse
// streaming; bypass L2 allocate/evict churn), all 8 loads issued before any
// store for max memory-level parallelism.

typedef float v4f __attribute__((ext_vector_type(4)));

__global__ __launch_bounds__(256) void cry_kernel(
    const float* __restrict__ xr_, const float* __restrict__ xi_,
    const float* __restrict__ ang_, float* __restrict__ out_)
{
    const unsigned tid = blockIdx.x * 256u + threadIdx.x;   // [0, 2^21) float4 units

    float sv, cv;
    __sincosf(0.5f * ang_[0], &sv, &cv);

    const v4f* xr  = (const v4f*)xr_;
    const v4f* xi  = (const v4f*)xi_;
    v4f*       out = (v4f*)out_;

    const unsigned Q  = 1u << 21;  // target-bit stride, float4 units (2^23 floats / 4)
    const unsigned CS = 1u << 22;  // control-bit stride, float4 units (2^24 floats / 4)
    const unsigned IM = 1u << 23;  // imag-half offset in out, float4 units (2^25 floats / 4)

    // ---- issue all 8 nontemporal loads up-front (max vmcnt in flight) ----
    v4f cr0 = __builtin_nontemporal_load(xr + tid);            // g=0, t=0, real
    v4f cr1 = __builtin_nontemporal_load(xr + tid + Q);        // g=0, t=1, real
    v4f ci0 = __builtin_nontemporal_load(xi + tid);            // g=0, t=0, imag
    v4f ci1 = __builtin_nontemporal_load(xi + tid + Q);        // g=0, t=1, imag
    v4f ar  = __builtin_nontemporal_load(xr + CS + tid);       // g=1, t=0, real
    v4f br  = __builtin_nontemporal_load(xr + CS + tid + Q);   // g=1, t=1, real
    v4f ai  = __builtin_nontemporal_load(xi + CS + tid);       // g=1, t=0, imag
    v4f bi  = __builtin_nontemporal_load(xi + CS + tid + Q);   // g=1, t=1, imag

    // ---- g=1: rotate target (levels 0,1) by theta/2; matrix is real, so
    //      identical linear combo on real and imag parts ----
    v4f rr0 = cv * ar - sv * br;
    v4f rr1 = cv * br - sv * ar;
    v4f ri0 = cv * ai - sv * bi;
    v4f ri1 = cv * bi - sv * ai;

    // ---- 8 nontemporal stores ----
    __builtin_nontemporal_store(cr0, out + tid);                // g=0 copy, real
    __builtin_nontemporal_store(cr1, out + tid + Q);
    __builtin_nontemporal_store(ci0, out + IM + tid);           // g=0 copy, imag
    __builtin_nontemporal_store(ci1, out + IM + tid + Q);
    __builtin_nontemporal_store(rr0, out + CS + tid);           // g=1 rot, real
    __builtin_nontemporal_store(rr1, out + CS + tid + Q);
    __builtin_nontemporal_store(ri0, out + IM + CS + tid);      // g=1 rot, imag
    __builtin_nontemporal_store(ri1, out + IM + CS + tid + Q);
}

extern "C" void kernel_launch(void* const* d_in, const int* in_sizes, int n_in,
                              void* d_out, int out_size, void* d_ws, size_t ws_size,
                              hipStream_t stream) {
    const float* xr  = (const float*)d_in[0];
    const float* xi  = (const float*)d_in[1];
    const float* ang = (const float*)d_in[2];
    float* out = (float*)d_out;

    // 2^21 threads, each handling one float4 per (g,t,part) octant
    const int threads = 256;
    const int blocks  = (1u << 21) / threads;  // 8192
    cry_kernel<<<blocks, threads, 0, stream>>>(xr, xi, ang, out);
}

// Round 2
// 419.020 us; speedup vs baseline: 1.0461x; 1.0377x over previous
//
#include <hip/hip_runtime.h>

// CRY gate, DIM=2, N=24, C=0, T=1, J=1, K=2, B=2.
// Float layout (floats): g stride 2^24, t stride 2^23, merged i=2s+b in [0,2^23).
// In float4 units: g stride CS=2^22, t stride Q=2^21, i4 in [0,2^21) per quadrant.
// Output: real half at 0, imag half at IM=2^23 float4 (2^25 floats).
//
// g=0 half is identity -> its output region is CONTIGUOUS per plane:
//   out[0 .. 2^22) f4           <- xr[0 .. 2^22)      (real plane)
//   out[IM .. IM+2^22) f4       <- xi[0 .. 2^22)      (imag plane)
// so it is served by pure linear-copy blocks (1 read stream + 1 write stream
// per wave -- the 6.3 TB/s copy-ubench structure).
// g=1 half needs the (t0,t1) pair: rotate blocks with 2 read + 2 write streams.
//
// Grid split (block-uniform, scalar branches):
//   bid in [0, 32768)      : copy, plane = bid>>14, off = (bid&16383)*256+lane
//   bid in [32768, 49152)  : rotate, rb=bid-32768, plane = rb>>13,
//                            off = (rb&8191)*256+lane

typedef float v4f __attribute__((ext_vector_type(4)));

__global__ __launch_bounds__(256) void cry_kernel(
    const float* __restrict__ xr_, const float* __restrict__ xi_,
    const float* __restrict__ ang_, float* __restrict__ out_)
{
    const unsigned bid  = blockIdx.x;
    const unsigned lane = threadIdx.x;

    const v4f* xr  = (const v4f*)xr_;
    const v4f* xi  = (const v4f*)xi_;
    v4f*       out = (v4f*)out_;

    const unsigned Q  = 1u << 21;  // target-bit stride, float4 units
    const unsigned CS = 1u << 22;  // control-bit stride, float4 units
    const unsigned IM = 1u << 23;  // imag-half offset in out, float4 units

    if (bid < 32768u) {
        // ---- g=0 identity: pure linear copy, 1 ld + 1 st per thread ----
        const unsigned plane = bid >> 14;                       // 0=real, 1=imag
        const unsigned off   = (bid & 16383u) * 256u + lane;    // [0, 2^22)
        const v4f* src = plane ? xi : xr;
        v4f v = __builtin_nontemporal_load(src + off);
        __builtin_nontemporal_store(v, out + plane * IM + off);
    } else {
        // ---- g=1 rotate: [out_t0; out_t1] = [[c,-s],[-s,c]] [a; b] ----
        float sv, cv;
        __sincosf(0.5f * ang_[0], &sv, &cv);
        const unsigned rb    = bid - 32768u;
        const unsigned plane = rb >> 13;                        // 0=real, 1=imag
        const unsigned off   = (rb & 8191u) * 256u + lane;      // [0, 2^21)
        const v4f* src = plane ? xi : xr;

        v4f a = __builtin_nontemporal_load(src + CS + off);      // t=0
        v4f b = __builtin_nontemporal_load(src + CS + off + Q);  // t=1

        v4f r0 = cv * a - sv * b;
        v4f r1 = cv * b - sv * a;

        v4f* dst = out + plane * IM + CS + off;
        __builtin_nontemporal_store(r0, dst);
        __builtin_nontemporal_store(r1, dst + Q);
    }
}

extern "C" void kernel_launch(void* const* d_in, const int* in_sizes, int n_in,
                              void* d_out, int out_size, void* d_ws, size_t ws_size,
                              hipStream_t stream) {
    const float* xr  = (const float*)d_in[0];
    const float* xi  = (const float*)d_in[1];
    const float* ang = (const float*)d_in[2];
    float* out = (float*)d_out;

    // 32768 copy blocks + 16384 rotate blocks
    const int threads = 256;
    const int blocks  = 32768 + 16384;  // 49152
    cry_kernel<<<blocks, threads, 0, stream>>>(xr, xi, ang, out);
}